// Round 1
// baseline (325.887 us; speedup 1.0000x reference)
//
#include <hip/hip_runtime.h>
#include <math.h>

namespace {
constexpr int B = 32, H = 56, W = 56, C = 256;
constexpr int HW  = H * W;      // 3136
constexpr int WC  = W * C;      // 14336
constexpr int HC  = H * C;      // 14336
constexpr int HWC = H * W * C;  // 802816
constexpr int CH  = 32;         // SE hidden
constexpr float BN_EPS = 1e-3f;

__device__ __forceinline__ float sigmoidf_(float v) { return 1.0f / (1.0f + expf(-v)); }
} // namespace

// ---------------- pool over W (branch1) + pool over C (branch3), one x pass ----
__global__ __launch_bounds__(256)
void pool13_kernel(const float* __restrict__ x,
                   float* __restrict__ pmax1, float* __restrict__ pavg1,
                   float* __restrict__ pmax3, float* __restrict__ pavg3) {
    const int b = blockIdx.x / H, h = blockIdx.x % H;
    const int t = threadIdx.x;
    const int lane = t & 63, sub = t >> 6;     // 4 waves, each owns w % 4 == sub
    const int c4 = lane * 4;
    const float* xp = x + (size_t)b * HWC + (size_t)h * WC;

    float4 mx = make_float4(-INFINITY, -INFINITY, -INFINITY, -INFINITY);
    float4 sm = make_float4(0.f, 0.f, 0.f, 0.f);
    for (int wq = 0; wq < 14; ++wq) {
        const int w = wq * 4 + sub;
        const float4 v = *(const float4*)(xp + w * C + c4);
        mx.x = fmaxf(mx.x, v.x); mx.y = fmaxf(mx.y, v.y);
        mx.z = fmaxf(mx.z, v.z); mx.w = fmaxf(mx.w, v.w);
        sm.x += v.x; sm.y += v.y; sm.z += v.z; sm.w += v.w;
        // pool3: reduce this (h,w) row over c across the wave (each wave owns distinct w)
        float m3 = fmaxf(fmaxf(v.x, v.y), fmaxf(v.z, v.w));
        float s3 = v.x + v.y + v.z + v.w;
        #pragma unroll
        for (int off = 32; off > 0; off >>= 1) {
            m3 = fmaxf(m3, __shfl_down(m3, off));
            s3 += __shfl_down(s3, off);
        }
        if (lane == 0) {
            pmax3[b * HW + h * W + w] = m3;
            pavg3[b * HW + h * W + w] = s3 * (1.0f / C);
        }
    }
    // combine the 4 per-sub partials for pool1
    __shared__ float smx[4][256];
    __shared__ float ssm[4][256];
    *(float4*)&smx[sub][c4] = mx;
    *(float4*)&ssm[sub][c4] = sm;
    __syncthreads();
    const float m = fmaxf(fmaxf(smx[0][t], smx[1][t]), fmaxf(smx[2][t], smx[3][t]));
    const float s = ssm[0][t] + ssm[1][t] + ssm[2][t] + ssm[3][t];
    pmax1[b * HC + h * C + t] = m;
    pavg1[b * HC + h * C + t] = s * (1.0f / W);
}

// ---------------- pool over H (branch2), stored transposed [b][w][c] ----------
__global__ __launch_bounds__(256)
void pool2_kernel(const float* __restrict__ x,
                  float* __restrict__ pmax2, float* __restrict__ pavg2) {
    const int b = blockIdx.x / W, w = blockIdx.x % W;
    const int t = threadIdx.x;
    const int lane = t & 63, sub = t >> 6;
    const int c4 = lane * 4;
    const float* xp = x + (size_t)b * HWC + (size_t)w * C;

    float4 mx = make_float4(-INFINITY, -INFINITY, -INFINITY, -INFINITY);
    float4 sm = make_float4(0.f, 0.f, 0.f, 0.f);
    for (int hq = 0; hq < 14; ++hq) {
        const int h = hq * 4 + sub;
        const float4 v = *(const float4*)(xp + (size_t)h * WC + c4);
        mx.x = fmaxf(mx.x, v.x); mx.y = fmaxf(mx.y, v.y);
        mx.z = fmaxf(mx.z, v.z); mx.w = fmaxf(mx.w, v.w);
        sm.x += v.x; sm.y += v.y; sm.z += v.z; sm.w += v.w;
    }
    __shared__ float smx[4][256];
    __shared__ float ssm[4][256];
    *(float4*)&smx[sub][c4] = mx;
    *(float4*)&ssm[sub][c4] = sm;
    __syncthreads();
    const float m = fmaxf(fmaxf(smx[0][t], smx[1][t]), fmaxf(smx[2][t], smx[3][t]));
    const float s = ssm[0][t] + ssm[1][t] + ssm[2][t] + ssm[3][t];
    pmax2[b * WC + w * C + t] = m;           // [b][w][c] layout
    pavg2[b * WC + w * C + t] = s * (1.0f / H);
}

// ---------------- conv1: spatial (H, C), output a1[b][h][c] -------------------
__global__ __launch_bounds__(256)
void conv1_kernel(const float* __restrict__ pmax, const float* __restrict__ pavg,
                  const float* __restrict__ cwt, const float* __restrict__ cb,
                  const float* __restrict__ g, const float* __restrict__ beta,
                  const float* __restrict__ mean, const float* __restrict__ var,
                  float* __restrict__ a1) {
    const int b = blockIdx.x / H, h = blockIdx.x % H;
    const int c = threadIdx.x;
    __shared__ float wg[98];
    if (c < 98) wg[c] = cwt[c];
    __syncthreads();
    const float A  = rsqrtf(var[0] + BN_EPS) * g[0];
    const float Bc = (cb[0] - mean[0]) * A + beta[0];
    float acc = 0.f;
    const float* bm = pmax + b * HC;
    const float* ba = pavg + b * HC;
    #pragma unroll
    for (int ky = 0; ky < 7; ++ky) {
        const int hy = h + ky - 3;
        if (hy < 0 || hy >= H) continue;
        const float* rm = bm + hy * C;
        const float* ra = ba + hy * C;
        #pragma unroll
        for (int kx = 0; kx < 7; ++kx) {
            const int cx = c + kx - 3;
            if (cx < 0 || cx >= C) continue;
            acc += rm[cx] * wg[ky * 14 + kx * 2] + ra[cx] * wg[ky * 14 + kx * 2 + 1];
        }
    }
    a1[b * HC + h * C + c] = sigmoidf_(acc * A + Bc);
}

// ---------------- conv2: spatial (C, W); pool stored [b][w][c]; out a2t[b][w][c]
__global__ __launch_bounds__(256)
void conv2_kernel(const float* __restrict__ pmax, const float* __restrict__ pavg,
                  const float* __restrict__ cwt, const float* __restrict__ cb,
                  const float* __restrict__ g, const float* __restrict__ beta,
                  const float* __restrict__ mean, const float* __restrict__ var,
                  float* __restrict__ a2t) {
    const int b = blockIdx.x / W, w = blockIdx.x % W;
    const int c = threadIdx.x;
    __shared__ float wg[98];
    if (c < 98) wg[c] = cwt[c];
    __syncthreads();
    const float A  = rsqrtf(var[0] + BN_EPS) * g[0];
    const float Bc = (cb[0] - mean[0]) * A + beta[0];
    float acc = 0.f;
    #pragma unroll
    for (int kx = 0; kx < 7; ++kx) {
        const int wx = w + kx - 3;
        if (wx < 0 || wx >= W) continue;
        const float* rm = pmax + b * WC + wx * C;
        const float* ra = pavg + b * WC + wx * C;
        #pragma unroll
        for (int ky = 0; ky < 7; ++ky) {
            const int cy = c + ky - 3;
            if (cy < 0 || cy >= C) continue;
            acc += rm[cy] * wg[ky * 14 + kx * 2] + ra[cy] * wg[ky * 14 + kx * 2 + 1];
        }
    }
    a2t[b * WC + w * C + c] = sigmoidf_(acc * A + Bc);
}

// ---------------- conv3: spatial (H, W), output a3[b][h][w] -------------------
__global__ __launch_bounds__(256)
void conv3_kernel(const float* __restrict__ pmax, const float* __restrict__ pavg,
                  const float* __restrict__ cwt, const float* __restrict__ cb,
                  const float* __restrict__ g, const float* __restrict__ beta,
                  const float* __restrict__ mean, const float* __restrict__ var,
                  float* __restrict__ a3) {
    const int b = blockIdx.x / 13;
    const int idx = (blockIdx.x % 13) * 256 + threadIdx.x;
    __shared__ float wg[98];
    if (threadIdx.x < 98) wg[threadIdx.x] = cwt[threadIdx.x];
    __syncthreads();
    if (idx >= HW) return;
    const int h = idx / W, w = idx % W;
    const float A  = rsqrtf(var[0] + BN_EPS) * g[0];
    const float Bc = (cb[0] - mean[0]) * A + beta[0];
    float acc = 0.f;
    const float* bm = pmax + b * HW;
    const float* ba = pavg + b * HW;
    #pragma unroll
    for (int ky = 0; ky < 7; ++ky) {
        const int hy = h + ky - 3;
        if (hy < 0 || hy >= H) continue;
        #pragma unroll
        for (int kx = 0; kx < 7; ++kx) {
            const int wx = w + kx - 3;
            if (wx < 0 || wx >= W) continue;
            acc += bm[hy * W + wx] * wg[ky * 14 + kx * 2] + ba[hy * W + wx] * wg[ky * 14 + kx * 2 + 1];
        }
    }
    a3[b * HW + idx] = sigmoidf_(acc * A + Bc);
}

// ---------------- gap[b][c] = mean_{h,w} x*(a1+a2+a3) -------------------------
__global__ __launch_bounds__(256)
void gap_kernel(const float* __restrict__ x, const float* __restrict__ a1,
                const float* __restrict__ a2t, const float* __restrict__ a3,
                float* __restrict__ gap) {
    const int b = blockIdx.x / H, h = blockIdx.x % H;
    const int t = threadIdx.x;
    const int lane = t & 63, sub = t >> 6;
    const int c4 = lane * 4;
    const float* xp  = x   + (size_t)b * HWC + (size_t)h * WC;
    const float* a2b = a2t + (size_t)b * WC;
    const float4 a1v = *(const float4*)(a1 + b * HC + h * C + c4);
    float4 acc = make_float4(0.f, 0.f, 0.f, 0.f);
    for (int wq = 0; wq < 14; ++wq) {
        const int w = wq * 4 + sub;
        const float4 xv  = *(const float4*)(xp  + w * C + c4);
        const float4 a2v = *(const float4*)(a2b + w * C + c4);
        const float a3v  = a3[b * HW + h * W + w];
        acc.x += xv.x * (a1v.x + a2v.x + a3v);
        acc.y += xv.y * (a1v.y + a2v.y + a3v);
        acc.z += xv.z * (a1v.z + a2v.z + a3v);
        acc.w += xv.w * (a1v.w + a2v.w + a3v);
    }
    __shared__ float sacc[4][256];
    *(float4*)&sacc[sub][c4] = acc;
    __syncthreads();
    const float s = sacc[0][t] + sacc[1][t] + sacc[2][t] + sacc[3][t];
    atomicAdd(&gap[b * C + t], s * (1.0f / (float)HW));
}

// ---------------- SE: 256 -> 32 -> 256 per batch ------------------------------
__global__ __launch_bounds__(256)
void se_kernel(const float* __restrict__ gap,
               const float* __restrict__ w1, const float* __restrict__ b1,
               const float* __restrict__ w2, const float* __restrict__ b2,
               float* __restrict__ cw) {
    const int b = blockIdx.x;
    const int t = threadIdx.x;
    __shared__ float gs[C];
    __shared__ float hs[CH];
    gs[t] = gap[b * C + t];
    __syncthreads();
    if (t < CH) {
        float a = b1[t];
        for (int c = 0; c < C; ++c) a += gs[c] * w1[c * CH + t];
        hs[t] = fmaxf(a, 0.f);
    }
    __syncthreads();
    float a = b2[t];
    #pragma unroll
    for (int d = 0; d < CH; ++d) a += hs[d] * w2[d * C + t];
    cw[b * C + t] = sigmoidf_(a);
}

// ---------------- out = x*(a1+a2+a3)*cw ---------------------------------------
__global__ __launch_bounds__(256)
void out_kernel(const float* __restrict__ x, const float* __restrict__ a1,
                const float* __restrict__ a2t, const float* __restrict__ a3,
                const float* __restrict__ cw, float* __restrict__ out) {
    const int r = blockIdx.x * 4 + (threadIdx.x >> 6);   // r over b*HW
    const int b = r / HW;
    const int hw = r % HW;
    const int h = hw / W, w = hw % W;
    const int c = (threadIdx.x & 63) * 4;
    const float4 xv  = *(const float4*)(x   + (size_t)r * C + c);
    const float4 a1v = *(const float4*)(a1  + b * HC + h * C + c);
    const float4 a2v = *(const float4*)(a2t + b * WC + w * C + c);
    const float  a3v = a3[r];
    const float4 cwv = *(const float4*)(cw  + b * C + c);
    float4 o;
    o.x = xv.x * (a1v.x + a2v.x + a3v) * cwv.x;
    o.y = xv.y * (a1v.y + a2v.y + a3v) * cwv.y;
    o.z = xv.z * (a1v.z + a2v.z + a3v) * cwv.z;
    o.w = xv.w * (a1v.w + a2v.w + a3v) * cwv.w;
    *(float4*)(out + (size_t)r * C + c) = o;
}

extern "C" void kernel_launch(void* const* d_in, const int* in_sizes, int n_in,
                              void* d_out, int out_size, void* d_ws, size_t ws_size,
                              hipStream_t stream) {
    const float* x = (const float*)d_in[0];
    // per-branch params: conv{i}_w, conv{i}_b, bn{i}_g, bn{i}_b, bn{i}_m, bn{i}_v
    const float* c1w = (const float*)d_in[1];  const float* c1b = (const float*)d_in[2];
    const float* g1  = (const float*)d_in[3];  const float* be1 = (const float*)d_in[4];
    const float* m1  = (const float*)d_in[5];  const float* v1  = (const float*)d_in[6];
    const float* c2w = (const float*)d_in[7];  const float* c2b = (const float*)d_in[8];
    const float* g2  = (const float*)d_in[9];  const float* be2 = (const float*)d_in[10];
    const float* m2  = (const float*)d_in[11]; const float* v2  = (const float*)d_in[12];
    const float* c3w = (const float*)d_in[13]; const float* c3b = (const float*)d_in[14];
    const float* g3  = (const float*)d_in[15]; const float* be3 = (const float*)d_in[16];
    const float* m3  = (const float*)d_in[17]; const float* v3  = (const float*)d_in[18];
    const float* sw1 = (const float*)d_in[19]; const float* sb1 = (const float*)d_in[20];
    const float* sw2 = (const float*)d_in[21]; const float* sb2 = (const float*)d_in[22];

    float* ws = (float*)d_ws;
    float* pmax1 = ws;                 // B*H*C
    float* pavg1 = pmax1 + (size_t)B * HC;
    float* pmax2 = pavg1 + (size_t)B * HC;   // [b][w][c]
    float* pavg2 = pmax2 + (size_t)B * WC;
    float* pmax3 = pavg2 + (size_t)B * WC;   // B*H*W
    float* pavg3 = pmax3 + (size_t)B * HW;
    float* a1    = pavg3 + (size_t)B * HW;   // [b][h][c]
    float* a2t   = a1    + (size_t)B * HC;   // [b][w][c]
    float* a3    = a2t   + (size_t)B * WC;   // [b][h][w]
    float* gap   = a3    + (size_t)B * HW;   // B*C
    float* cwv   = gap   + (size_t)B * C;    // B*C

    hipMemsetAsync(gap, 0, (size_t)B * C * sizeof(float), stream);

    pool13_kernel<<<B * H, 256, 0, stream>>>(x, pmax1, pavg1, pmax3, pavg3);
    pool2_kernel <<<B * W, 256, 0, stream>>>(x, pmax2, pavg2);
    conv1_kernel <<<B * H, 256, 0, stream>>>(pmax1, pavg1, c1w, c1b, g1, be1, m1, v1, a1);
    conv2_kernel <<<B * W, 256, 0, stream>>>(pmax2, pavg2, c2w, c2b, g2, be2, m2, v2, a2t);
    conv3_kernel <<<B * 13, 256, 0, stream>>>(pmax3, pavg3, c3w, c3b, g3, be3, m3, v3, a3);
    gap_kernel   <<<B * H, 256, 0, stream>>>(x, a1, a2t, a3, gap);
    se_kernel    <<<B, 256, 0, stream>>>(gap, sw1, sb1, sw2, sb2, cwv);
    out_kernel   <<<B * HW / 4, 256, 0, stream>>>(x, a1, a2t, a3, cwv, (float*)d_out);
}